// Round 18
// baseline (216.414 us; speedup 1.0000x reference)
//
#include <hip/hip_runtime.h>
#include <hip/hip_bf16.h>
#include <math.h>

#define B_SZ 4
#define C_SZ 512
#define N_SZ 4096
#define D_SZ 64
#define SHIFT 60.0f

typedef __attribute__((ext_vector_type(4))) float f32x4;
typedef __attribute__((ext_vector_type(8))) short bf16x8;
typedef __attribute__((ext_vector_type(4))) short s16x4;
typedef __attribute__((ext_vector_type(8))) _Float16 f16x8;

// fp32 -> bf16 RNE via native convert
__device__ __forceinline__ short f2bf(float x) {
    return (short)__bfloat16_as_ushort(__float2bfloat16(x));
}

__device__ __forceinline__ bf16x8 pack8(float4 a, float4 b) {
    bf16x8 r;
    r[0] = f2bf(a.x); r[1] = f2bf(a.y); r[2] = f2bf(a.z); r[3] = f2bf(a.w);
    r[4] = f2bf(b.x); r[5] = f2bf(b.y); r[6] = f2bf(b.z); r[7] = f2bf(b.w);
    return r;
}

// fp32x8 -> fp16x8 (RNE)
__device__ __forceinline__ f16x8 pack8h(float4 a, float4 b) {
    f16x8 r;
    r[0] = (_Float16)a.x; r[1] = (_Float16)a.y; r[2] = (_Float16)a.z; r[3] = (_Float16)a.w;
    r[4] = (_Float16)b.x; r[5] = (_Float16)b.y; r[6] = (_Float16)b.z; r[7] = (_Float16)b.w;
    return r;
}

#define A_BLOCKS ((B_SZ * C_SZ * N_SZ) / (256 * 8))   // 4096
#define C_BLOCKS ((B_SZ * N_SZ * D_SZ) / (256 * 8))   // 512

// ---------------------------------------------------------------------------
// Merged pre-pass: a fp32 -> bf16 ; c fp32 -> fp16 (one launch)
// ---------------------------------------------------------------------------
__global__ __launch_bounds__(256) void conv_kernel(
    const float* __restrict__ amat, const float* __restrict__ cmat,
    short* __restrict__ abf, _Float16* __restrict__ chm)
{
    const int bid = blockIdx.x;
    if (bid < A_BLOCKS) {
        size_t i = ((size_t)bid * 256 + threadIdx.x) * 8;
        float4 a0 = ((const float4*)(amat + i))[0];
        float4 a1 = ((const float4*)(amat + i))[1];
        *(bf16x8*)(abf + i) = pack8(a0, a1);
    } else {
        size_t i = ((size_t)(bid - A_BLOCKS) * 256 + threadIdx.x) * 8;
        float4 c0 = ((const float4*)(cmat + i))[0];
        float4 c1 = ((const float4*)(cmat + i))[1];
        *(f16x8*)(chm + i) = pack8h(c0, c1);
    }
}

// ---------------------------------------------------------------------------
// Fused pass (pv12): R15 (swapped QK, 4 waves, 256ch x 64m, 4 P buffers,
// barrier per 128-n segment) + af-ONLY register prefetch (named buffers)
// under __launch_bounds__(256, 1):
//   - (256,2) capped the VGPR class at 128 (AGPR acc eats the 2-wave budget)
//     and spilled in R13/R17; min-1 lifts the cap. Demand ~130 class + 64
//     AGPR ~ 195/wave <= 256 -> still 2 waves/SIMD at runtime.
//   - K loads stay at-use (post-barrier slack absorbs their latency).
// ---------------------------------------------------------------------------
__global__ __launch_bounds__(256, 1) void pv12_kernel(
    const float* __restrict__ amat, const float* __restrict__ bmat,
    const short* __restrict__ abf, const _Float16* __restrict__ chm,
    float* __restrict__ out)
{
    const int t = threadIdx.x;
    const int lane = t & 63;
    const int l15 = lane & 15;
    const int lg = lane >> 4;
    const int w = t >> 6;

    const int bid = blockIdx.x;
    const int slice = bid & 7;         // -> XCD via dispatch round-robin
    const int gm0 = (bid >> 3) * 64;   // m-tile
    const int gc0 = (slice & 1) * 256; // ch half
    const int bz = slice >> 1;         // batch

    __shared__ __align__(16) short smp[4][64 * 72];  // P [m][n], 4 buffers
    __shared__ float ldsL4[4][64];

    // Q fragments (B-operand of swapped QK)
    f16x8 qf[4][2];
#pragma unroll
    for (int mf = 0; mf < 4; ++mf)
#pragma unroll
        for (int kf = 0; kf < 2; ++kf) {
            const float* qp = bmat + ((size_t)bz * N_SZ + gm0 + mf * 16 + l15) * D_SZ
                              + kf * 32 + lg * 8;
            float4 q0 = ((const float4*)qp)[0];
            float4 q1 = ((const float4*)qp)[1];
            qf[mf][kf] = pack8h(q0, q1);
        }

    f32x4 acc[4][4];
#pragma unroll
    for (int i = 0; i < 4; ++i)
#pragma unroll
        for (int j = 0; j < 4; ++j)
            acc[i][j] = (f32x4){0.f, 0.f, 0.f, 0.f};

    float psum[4] = {0.f, 0.f, 0.f, 0.f};

    // K-fragment base (MFMA A): c row (w*16 + l15), d-octet lg*8
    const _Float16* kb = chm + ((size_t)bz * N_SZ + w * 16 + l15) * D_SZ + lg * 8;
    // af base (PV A): a row (gc0 + w*64 + l15), n-octet lg*8
    const short* ab = abf + ((size_t)bz * C_SZ + gc0 + w * 64 + l15) * N_SZ + lg * 8;

    // af prefetch: NAMED double buffer (rule #20). afr0 = even chunk of the
    // current segment, afr1 = odd chunk, roles fixed for all segments.
    bf16x8 afr0[4][2], afr1[4][2];

    auto LOADAF = [&](int n0, bf16x8 (&dst)[4][2]) {
#pragma unroll
        for (int chf = 0; chf < 4; ++chf)
#pragma unroll
            for (int kf = 0; kf < 2; ++kf)
                dst[chf][kf] =
                    *(const bf16x8*)(ab + (size_t)chf * 16 * N_SZ + n0 + kf * 32);
    };

    // swapped QK: K loaded at use -> P into smp[pbuf] as b64 stores
    auto QK = [&](int n0, int pbuf) {
        const _Float16* kp = kb + (size_t)n0 * D_SZ;
        f16x8 k0 = *(const f16x8*)(kp);
        f16x8 k1 = *(const f16x8*)(kp + 32);
#pragma unroll
        for (int mf = 0; mf < 4; ++mf) {
            f32x4 s = {0.f, 0.f, 0.f, 0.f};
            s = __builtin_amdgcn_mfma_f32_16x16x32_f16(k0, qf[mf][0], s, 0, 0, 0);
            s = __builtin_amdgcn_mfma_f32_16x16x32_f16(k1, qf[mf][1], s, 0, 0, 0);
            // lane: P[n = w*16 + lg*4 + r][m = mf*16 + l15]
            float p0 = __expf(s[0] - SHIFT);
            float p1 = __expf(s[1] - SHIFT);
            float p2 = __expf(s[2] - SHIFT);
            float p3 = __expf(s[3] - SHIFT);
            psum[mf] += (p0 + p1) + (p2 + p3);
            s16x4 pw;
            pw[0] = f2bf(p0); pw[1] = f2bf(p1); pw[2] = f2bf(p2); pw[3] = f2bf(p3);
            *(s16x4*)&smp[pbuf][(mf * 16 + l15) * 72 + w * 16 + lg * 4] = pw;
        }
    };

    // PV: af from named reg buffer, P from smp[pbuf]
    auto PV = [&](int pbuf, bf16x8 (&af)[4][2]) {
#pragma unroll
        for (int kf = 0; kf < 2; ++kf) {
            bf16x8 pf[4];
#pragma unroll
            for (int mf = 0; mf < 4; ++mf)
                pf[mf] = *(const bf16x8*)&smp[pbuf][(mf * 16 + l15) * 72 + kf * 32 + lg * 8];
#pragma unroll
            for (int chf = 0; chf < 4; ++chf)
#pragma unroll
                for (int mf = 0; mf < 4; ++mf)
                    acc[chf][mf] = __builtin_amdgcn_mfma_f32_16x16x32_bf16(
                        af[chf][kf], pf[mf], acc[chf][mf], 0, 0, 0);
        }
    };

    // segment s: PV chunks 2s (afr0), 2s+1 (afr1); QK chunks 2s+2, 2s+3.
    // afr1 load issued at segment start; afr0 (next seg's even chunk)
    // issued mid-segment -> a full PV+2QK phase of latency cover.
    auto SEG = [&](int s, int p0, int p1, int p2, int p3) {
        __syncthreads();
        LOADAF(s * 128 + 64, afr1);
        PV(p0, afr0);
        LOADAF(s * 128 + 128, afr0);
        PV(p1, afr1);
        QK((s + 1) * 128, p2);
        QK((s + 1) * 128 + 64, p3);
    };

    // prologue
    QK(0, 0);
    QK(64, 1);
    LOADAF(0, afr0);

    for (int sp = 0; sp < 15; ++sp) {
        SEG(2 * sp,     0, 1, 2, 3);
        SEG(2 * sp + 1, 2, 3, 0, 1);
    }
    SEG(30, 0, 1, 2, 3);          // PV ch60,61; QK ch62,63; afr0 <- ch62

    __syncthreads();
    LOADAF(4032, afr1);           // chunk 63
    PV(2, afr0);                  // chunk 62
    PV(3, afr1);                  // chunk 63

    // L reduction: sum over lg groups (xor 16, 32), then cross-wave via LDS.
#pragma unroll
    for (int mf = 0; mf < 4; ++mf) {
        float v = psum[mf];
        v += __shfl_xor(v, 16, 64);
        v += __shfl_xor(v, 32, 64);
        if (lg == 0) ldsL4[w][mf * 16 + l15] = v;
    }
    __syncthreads();

    float ri[4];
#pragma unroll
    for (int mf = 0; mf < 4; ++mf) {
        int m = mf * 16 + l15;
        ri[mf] = 1.0f / (ldsL4[0][m] + ldsL4[1][m] + ldsL4[2][m] + ldsL4[3][m]);
    }

    // epilogue: out = acc / L + a
#pragma unroll
    for (int chf = 0; chf < 4; ++chf)
#pragma unroll
        for (int mf = 0; mf < 4; ++mf) {
            const int m = gm0 + mf * 16 + l15;
#pragma unroll
            for (int r = 0; r < 4; ++r) {
                const int ch = gc0 + w * 64 + chf * 16 + lg * 4 + r;
                size_t o = ((size_t)bz * C_SZ + ch) * N_SZ + m;
                out[o] = acc[chf][mf][r] * ri[mf] + amat[o];
            }
        }
}

extern "C" void kernel_launch(void* const* d_in, const int* in_sizes, int n_in,
                              void* d_out, int out_size, void* d_ws, size_t ws_size,
                              hipStream_t stream) {
    const float* a = (const float*)d_in[0];
    const float* b = (const float*)d_in[1];
    const float* c = (const float*)d_in[2];
    float* out = (float*)d_out;

    // ws layout: abf (bf16, 8 MB) | c fp16 (2 MB)
    const size_t abf_b = (size_t)B_SZ * C_SZ * N_SZ * 2;

    short* abf = (short*)d_ws;
    _Float16* chm = (_Float16*)((char*)d_ws + abf_b);

    conv_kernel<<<dim3(A_BLOCKS + C_BLOCKS), 256, 0, stream>>>(a, c, abf, chm);
    pv12_kernel<<<dim3(512), 256, 0, stream>>>(a, b, abf, chm, out);
}

// Round 19
// 165.875 us; speedup vs baseline: 1.3047x; 1.3047x over previous
//
#include <hip/hip_runtime.h>
#include <hip/hip_bf16.h>
#include <math.h>

#define B_SZ 4
#define C_SZ 512
#define N_SZ 4096
#define D_SZ 64
#define SHIFT 60.0f

typedef __attribute__((ext_vector_type(4))) float f32x4;
typedef __attribute__((ext_vector_type(8))) short bf16x8;
typedef __attribute__((ext_vector_type(4))) short s16x4;
typedef __attribute__((ext_vector_type(8))) _Float16 f16x8;

// fp32 -> bf16 RNE via native convert
__device__ __forceinline__ short f2bf(float x) {
    return (short)__bfloat16_as_ushort(__float2bfloat16(x));
}

__device__ __forceinline__ bf16x8 pack8(float4 a, float4 b) {
    bf16x8 r;
    r[0] = f2bf(a.x); r[1] = f2bf(a.y); r[2] = f2bf(a.z); r[3] = f2bf(a.w);
    r[4] = f2bf(b.x); r[5] = f2bf(b.y); r[6] = f2bf(b.z); r[7] = f2bf(b.w);
    return r;
}

// fp32x8 -> fp16x8 (RNE)
__device__ __forceinline__ f16x8 pack8h(float4 a, float4 b) {
    f16x8 r;
    r[0] = (_Float16)a.x; r[1] = (_Float16)a.y; r[2] = (_Float16)a.z; r[3] = (_Float16)a.w;
    r[4] = (_Float16)b.x; r[5] = (_Float16)b.y; r[6] = (_Float16)b.z; r[7] = (_Float16)b.w;
    return r;
}

#define A_BLOCKS ((B_SZ * C_SZ * N_SZ) / (256 * 8))   // 4096
#define C_BLOCKS ((B_SZ * N_SZ * D_SZ) / (256 * 8))   // 512

// ---------------------------------------------------------------------------
// Merged pre-pass: a fp32 -> bf16 ; c fp32 -> fp16 (one launch)
// ---------------------------------------------------------------------------
__global__ __launch_bounds__(256) void conv_kernel(
    const float* __restrict__ amat, const float* __restrict__ cmat,
    short* __restrict__ abf, _Float16* __restrict__ chm)
{
    const int bid = blockIdx.x;
    if (bid < A_BLOCKS) {
        size_t i = ((size_t)bid * 256 + threadIdx.x) * 8;
        float4 a0 = ((const float4*)(amat + i))[0];
        float4 a1 = ((const float4*)(amat + i))[1];
        *(bf16x8*)(abf + i) = pack8(a0, a1);
    } else {
        size_t i = ((size_t)(bid - A_BLOCKS) * 256 + threadIdx.x) * 8;
        float4 c0 = ((const float4*)(cmat + i))[0];
        float4 c1 = ((const float4*)(cmat + i))[1];
        *(f16x8*)(chm + i) = pack8h(c0, c1);
    }
}

// ---------------------------------------------------------------------------
// Fused pass (pv13): R15 structure (swapped fp16 QK, 4 waves, 256ch x 64m,
// 4 P buffers, barrier per 128-n segment, load-at-use) with the segment body
// INTERLEAVED at half-chunk granularity:
//   QK(c2,mf01) -> PV(p0,kf0) -> QK(c2,mf23) -> PV(p0,kf1)
//   QK(c3,mf01) -> PV(p1,kf0) -> QK(c3,mf23) -> PV(p1,kf1)
// so each QK exp/cvt chain has 16 independent PV MFMAs to hide under
// (compiler can't do this itself: runtime-indexed smp buffers block DS
// reordering). PV MFMA clusters wrapped in s_setprio(1) (T5).
// ---------------------------------------------------------------------------
__global__ __launch_bounds__(256, 2) void pv13_kernel(
    const float* __restrict__ amat, const float* __restrict__ bmat,
    const short* __restrict__ abf, const _Float16* __restrict__ chm,
    float* __restrict__ out)
{
    const int t = threadIdx.x;
    const int lane = t & 63;
    const int l15 = lane & 15;
    const int lg = lane >> 4;
    const int w = t >> 6;

    const int bid = blockIdx.x;
    const int slice = bid & 7;         // -> XCD via dispatch round-robin
    const int gm0 = (bid >> 3) * 64;   // m-tile
    const int gc0 = (slice & 1) * 256; // ch half
    const int bz = slice >> 1;         // batch

    __shared__ __align__(16) short smp[4][64 * 72];  // P [m][n], 4 buffers
    __shared__ float ldsL4[4][64];

    // Q fragments (B-operand of swapped QK)
    f16x8 qf[4][2];
#pragma unroll
    for (int mf = 0; mf < 4; ++mf)
#pragma unroll
        for (int kf = 0; kf < 2; ++kf) {
            const float* qp = bmat + ((size_t)bz * N_SZ + gm0 + mf * 16 + l15) * D_SZ
                              + kf * 32 + lg * 8;
            float4 q0 = ((const float4*)qp)[0];
            float4 q1 = ((const float4*)qp)[1];
            qf[mf][kf] = pack8h(q0, q1);
        }

    f32x4 acc[4][4];
#pragma unroll
    for (int i = 0; i < 4; ++i)
#pragma unroll
        for (int j = 0; j < 4; ++j)
            acc[i][j] = (f32x4){0.f, 0.f, 0.f, 0.f};

    float psum[4] = {0.f, 0.f, 0.f, 0.f};

    // K-fragment base (MFMA A): c row (w*16 + l15), d-octet lg*8
    const _Float16* kb = chm + ((size_t)bz * N_SZ + w * 16 + l15) * D_SZ + lg * 8;
    // af base (PV A): a row (gc0 + w*64 + l15), n-octet lg*8
    const short* ab = abf + ((size_t)bz * C_SZ + gc0 + w * 64 + l15) * N_SZ + lg * 8;

    // QK half: rows mf0, mf0+1 of the swapped score tile for K frags k0,k1
    auto QKh = [&](f16x8 k0, f16x8 k1, int pbuf, int mf0) {
#pragma unroll
        for (int mi = 0; mi < 2; ++mi) {
            const int mf = mf0 + mi;
            f32x4 s = {0.f, 0.f, 0.f, 0.f};
            s = __builtin_amdgcn_mfma_f32_16x16x32_f16(k0, qf[mf][0], s, 0, 0, 0);
            s = __builtin_amdgcn_mfma_f32_16x16x32_f16(k1, qf[mf][1], s, 0, 0, 0);
            float p0 = __expf(s[0] - SHIFT);
            float p1 = __expf(s[1] - SHIFT);
            float p2 = __expf(s[2] - SHIFT);
            float p3 = __expf(s[3] - SHIFT);
            psum[mf] += (p0 + p1) + (p2 + p3);
            s16x4 pw;
            pw[0] = f2bf(p0); pw[1] = f2bf(p1); pw[2] = f2bf(p2); pw[3] = f2bf(p3);
            *(s16x4*)&smp[pbuf][(mf * 16 + l15) * 72 + w * 16 + lg * 4] = pw;
        }
    };

    // PV half: one kf pass (4 pf reads, 4 af loads, 16 MFMA under setprio)
    auto PVh = [&](int n0, int pbuf, int kf) {
        bf16x8 pf[4], af[4];
#pragma unroll
        for (int mf = 0; mf < 4; ++mf)
            pf[mf] = *(const bf16x8*)&smp[pbuf][(mf * 16 + l15) * 72 + kf * 32 + lg * 8];
#pragma unroll
        for (int chf = 0; chf < 4; ++chf)
            af[chf] = *(const bf16x8*)(ab + (size_t)chf * 16 * N_SZ + n0 + kf * 32);
        __builtin_amdgcn_s_setprio(1);
#pragma unroll
        for (int chf = 0; chf < 4; ++chf)
#pragma unroll
            for (int mf = 0; mf < 4; ++mf)
                acc[chf][mf] = __builtin_amdgcn_mfma_f32_16x16x32_bf16(
                    af[chf], pf[mf], acc[chf][mf], 0, 0, 0);
        __builtin_amdgcn_s_setprio(0);
    };

    // segment s: PV chunks 2s (p0), 2s+1 (p1) interleaved with QK of
    // chunks 2s+2 (p2), 2s+3 (p3)
    auto SEG = [&](int s, int p0, int p1, int p2, int p3) {
        __syncthreads();
        const int c0n = s * 128, c1n = c0n + 64;
        const int c2n = c0n + 128, c3n = c0n + 192;
        {
            const _Float16* kp = kb + (size_t)c2n * D_SZ;
            f16x8 k0 = *(const f16x8*)(kp);
            f16x8 k1 = *(const f16x8*)(kp + 32);
            QKh(k0, k1, p2, 0);
            PVh(c0n, p0, 0);
            QKh(k0, k1, p2, 2);
            PVh(c0n, p0, 1);
        }
        {
            const _Float16* kp = kb + (size_t)c3n * D_SZ;
            f16x8 k0 = *(const f16x8*)(kp);
            f16x8 k1 = *(const f16x8*)(kp + 32);
            QKh(k0, k1, p3, 0);
            PVh(c1n, p1, 0);
            QKh(k0, k1, p3, 2);
            PVh(c1n, p1, 1);
        }
    };

    // prologue: QK chunks 0,1 -> bufs 0,1
    {
        const _Float16* kp = kb;
        f16x8 k0 = *(const f16x8*)(kp);
        f16x8 k1 = *(const f16x8*)(kp + 32);
        QKh(k0, k1, 0, 0);
        QKh(k0, k1, 0, 2);
        kp = kb + (size_t)64 * D_SZ;
        k0 = *(const f16x8*)(kp);
        k1 = *(const f16x8*)(kp + 32);
        QKh(k0, k1, 1, 0);
        QKh(k0, k1, 1, 2);
    }

    for (int sp = 0; sp < 15; ++sp) {
        SEG(2 * sp,     0, 1, 2, 3);
        SEG(2 * sp + 1, 2, 3, 0, 1);
    }
    SEG(30, 0, 1, 2, 3);          // PV ch60,61; QK ch62,63 -> bufs 2,3

    __syncthreads();
    PVh(62 * 64, 2, 0);
    PVh(62 * 64, 2, 1);
    PVh(63 * 64, 3, 0);
    PVh(63 * 64, 3, 1);

    // L reduction: sum over lg groups (xor 16, 32), then cross-wave via LDS.
#pragma unroll
    for (int mf = 0; mf < 4; ++mf) {
        float v = psum[mf];
        v += __shfl_xor(v, 16, 64);
        v += __shfl_xor(v, 32, 64);
        if (lg == 0) ldsL4[w][mf * 16 + l15] = v;
    }
    __syncthreads();

    float ri[4];
#pragma unroll
    for (int mf = 0; mf < 4; ++mf) {
        int m = mf * 16 + l15;
        ri[mf] = 1.0f / (ldsL4[0][m] + ldsL4[1][m] + ldsL4[2][m] + ldsL4[3][m]);
    }

    // epilogue: out = acc / L + a
#pragma unroll
    for (int chf = 0; chf < 4; ++chf)
#pragma unroll
        for (int mf = 0; mf < 4; ++mf) {
            const int m = gm0 + mf * 16 + l15;
#pragma unroll
            for (int r = 0; r < 4; ++r) {
                const int ch = gc0 + w * 64 + chf * 16 + lg * 4 + r;
                size_t o = ((size_t)bz * C_SZ + ch) * N_SZ + m;
                out[o] = acc[chf][mf][r] * ri[mf] + amat[o];
            }
        }
}

extern "C" void kernel_launch(void* const* d_in, const int* in_sizes, int n_in,
                              void* d_out, int out_size, void* d_ws, size_t ws_size,
                              hipStream_t stream) {
    const float* a = (const float*)d_in[0];
    const float* b = (const float*)d_in[1];
    const float* c = (const float*)d_in[2];
    float* out = (float*)d_out;

    // ws layout: abf (bf16, 8 MB) | c fp16 (2 MB)
    const size_t abf_b = (size_t)B_SZ * C_SZ * N_SZ * 2;

    short* abf = (short*)d_ws;
    _Float16* chm = (_Float16*)((char*)d_ws + abf_b);

    conv_kernel<<<dim3(A_BLOCKS + C_BLOCKS), 256, 0, stream>>>(a, c, abf, chm);
    pv13_kernel<<<dim3(512), 256, 0, stream>>>(a, b, abf, chm, out);
}